// Round 3
// baseline (7336.429 us; speedup 1.0000x reference)
//
#include <hip/hip_runtime.h>
#include <stdint.h>

typedef unsigned int   u32;
typedef unsigned short u16;
typedef __attribute__((ext_vector_type(8))) short bf16x8;   // 8 bf16 = 4 VGPRs
typedef __attribute__((ext_vector_type(4))) float f32x4;

#define DEV __device__ __forceinline__

// ---------------- problem sizes ----------------
constexpr int Bsz = 64, Ssz = 512, INsz = 1024, Hsz = 1024, OUTsz = 512;
constexpr int G3 = 3 * Hsz;            // 3072
constexpr int MR = Bsz * Ssz;          // 32768
constexpr int TCH = 64;                // timesteps per chunk
constexpr int NCH = Ssz / TCH;         // 8 chunks
constexpr int MCH = Bsz * TCH;         // 4096 rows per chunk

// ---------------- workspace layout (bytes), total ~154.5 MiB ----------------
constexpr size_t WHHHI_OFF = 0;
constexpr size_t WHHLO_OFF = WHHHI_OFF + (size_t)G3 * Hsz * 2;      //  6 MiB each
constexpr size_t WIHHI_OFF = WHHLO_OFF + (size_t)G3 * Hsz * 2;
constexpr size_t WIHLO_OFF = WIHHI_OFF + (size_t)G3 * INsz * 2;
constexpr size_t WOHI_OFF  = WIHLO_OFF + (size_t)G3 * INsz * 2;
constexpr size_t WOLO_OFF  = WOHI_OFF  + (size_t)OUTsz * Hsz * 2;   //  1 MiB each
constexpr size_t HS_OFF    = WOLO_OFF  + (size_t)OUTsz * Hsz * 2;   // 64 MiB single-bf16 hs
constexpr size_t HP_OFF    = HS_OFF    + (size_t)MR * Hsz * 2;      // 4 ping-pong planes
constexpr size_t HPL       = (size_t)Bsz * Hsz;                     // u16 elems per plane
constexpr size_t XCHI_OFF  = HP_OFF   + 4 * HPL * 2;                // 8 MiB each
constexpr size_t XCLO_OFF  = XCHI_OFF + (size_t)MCH * INsz * 2;
constexpr size_t XGC_OFF   = XCLO_OFF + (size_t)MCH * INsz * 2;     // 48 MiB fp32 xg chunk
constexpr size_t WS_TOTAL  = XGC_OFF  + (size_t)MCH * G3 * 4;       // 162,004,992 B

// ---------------- fp32 <-> split-bf16 helpers ----------------
DEV u16 f2bf(float f) {
  u32 u = __float_as_uint(f);
  u += 0x7fffu + ((u >> 16) & 1u);     // RNE
  return (u16)(u >> 16);
}
DEV float bf2f(u16 h) { return __uint_as_float((u32)h << 16); }
DEV void split2(float v, u16& hi, u16& lo) {
  hi = f2bf(v);
  lo = f2bf(v - bf2f(hi));
}

// ---------------- diag: report ws_size (MiB) via absmax when scratch too small ----------------
__global__ void diag_ws(float* out, float v) { out[0] = v; }

// ---------------- prep: split weights once ----------------
__global__ void prep_w(const float* __restrict__ wih, const float* __restrict__ whh,
                       const float* __restrict__ wout,
                       u16* __restrict__ wihhi, u16* __restrict__ wihlo,
                       u16* __restrict__ whhhi, u16* __restrict__ whhlo,
                       u16* __restrict__ wohi, u16* __restrict__ wolo) {
  const size_t n1 = (size_t)G3 * INsz;
  const size_t n2 = n1 + (size_t)G3 * Hsz;
  const size_t n3 = n2 + (size_t)OUTsz * Hsz;
  size_t i = (size_t)blockIdx.x * blockDim.x + threadIdx.x;
  const size_t stride = (size_t)gridDim.x * blockDim.x;
  for (; i < n3; i += stride) {
    const float* s; u16 *ph, *pl; size_t j;
    if (i < n1)      { s = wih;  ph = wihhi; pl = wihlo; j = i; }
    else if (i < n2) { s = whh;  ph = whhhi; pl = whhlo; j = i - n1; }
    else             { s = wout; ph = wohi;  pl = wolo;  j = i - n2; }
    u16 hi, lo; split2(s[j], hi, lo);
    ph[j] = hi; pl[j] = lo;
  }
}

// ---------------- prep: split one x-chunk  x[:, t0:t0+64, :] -> planes [b*64+tc][k] ----------------
__global__ void prep_x(const float* __restrict__ x, int t0,
                       u16* __restrict__ xchi, u16* __restrict__ xclo) {
  const size_t total = (size_t)MCH * INsz;
  size_t i = (size_t)blockIdx.x * blockDim.x + threadIdx.x;
  const size_t stride = (size_t)gridDim.x * blockDim.x;
  for (; i < total; i += stride) {
    const int k = (int)(i & 1023), tc = (int)((i >> 10) & (TCH - 1)), b = (int)(i >> 16);
    const float v = x[((size_t)b * Ssz + t0 + tc) * INsz + k];
    u16 hi, lo; split2(v, hi, lo);
    xchi[i] = hi; xclo[i] = lo;        // i == (b*64+tc)*1024 + k
  }
}

// ---------------- GEMM:  C[M][N] = A[M][K=1024] * W[N][K]^T + bias ----------------
// m97 structure: 128x128 tile, BK=64, global_load_lds w16, source-pre-swizzled LDS (T2).
// SPLITA: A given as hi+lo planes (3 MFMA); else single bf16 A (2 MFMA). B always hi+lo.
template <bool SPLITA>
__global__ __launch_bounds__(256, 2)
void gemm_ws(const u16* __restrict__ Ahi, const u16* __restrict__ Alo,
             const u16* __restrict__ Bhi, const u16* __restrict__ Blo,
             const float* __restrict__ bias,
             float* __restrict__ C, int M, int N) {
  constexpr int K = 1024;
  constexpr int NT = SPLITA ? 4 : 3;                  // tiles: [Ahi,(Alo),Bhi,Blo]
  __shared__ __align__(16) u16 smem[NT * 128 * 64];   // 16 KiB per tile
  const int tid = threadIdx.x, lane = tid & 63, wid = tid >> 6;

  int wg = blockIdx.x;
  const int cpx = (int)gridDim.x >> 3;                // grid % 8 == 0 at all call sites
  wg = (wg & 7) * cpx + (wg >> 3);
  const int NB = N >> 7;
  const int mb = wg / NB, nb = wg % NB;
  const size_t m0 = (size_t)mb * 128, n0 = (size_t)nb * 128;
  const int wm = wid >> 1, wn = wid & 1;

  f32x4 acc[4][4];
#pragma unroll
  for (int i = 0; i < 4; ++i)
#pragma unroll
    for (int j = 0; j < 4; ++j) acc[i][j] = (f32x4)0.f;

  for (int k0 = 0; k0 < K; k0 += 64) {
    __syncthreads();
#pragma unroll
    for (int is = 0; is < NT * 4; ++is) {
      const int g = is * 256 + wid * 64 + lane;       // 16B granule id (wave-uniform tile)
      const int tile = g >> 10;
      const int gi = g & 1023;
      const int row = gi >> 3, gcd = gi & 7;
      const int gcs = gcd ^ (row & 7);                // inverse-swizzled source granule
      const u16* src;
      if (SPLITA) {
        if (tile == 0)      src = Ahi + (m0 + row) * K + (k0 + gcs * 8);
        else if (tile == 1) src = Alo + (m0 + row) * K + (k0 + gcs * 8);
        else if (tile == 2) src = Bhi + (n0 + row) * K + (k0 + gcs * 8);
        else                src = Blo + (n0 + row) * K + (k0 + gcs * 8);
      } else {
        if (tile == 0)      src = Ahi + (m0 + row) * K + (k0 + gcs * 8);
        else if (tile == 1) src = Bhi + (n0 + row) * K + (k0 + gcs * 8);
        else                src = Blo + (n0 + row) * K + (k0 + gcs * 8);
      }
      __builtin_amdgcn_global_load_lds(
          (const __attribute__((address_space(1))) void*)src,
          (__attribute__((address_space(3))) void*)&smem[(size_t)(is * 256 + wid * 64) * 8],
          16, 0, 0);
    }
    __syncthreads();

    constexpr int BH_T = SPLITA ? 2 : 1;              // Bhi tile index
#pragma unroll
    for (int kt = 0; kt < 2; ++kt) {
      bf16x8 ah[4], al[4], bh[4], bl[4];
      const int gc = kt * 4 + (lane >> 4);
#pragma unroll
      for (int i = 0; i < 4; ++i) {
        const int row = wm * 64 + i * 16 + (lane & 15);
        const int off = row * 128 + ((gc ^ (row & 7)) << 4);
        ah[i] = *(const bf16x8*)((const char*)smem + off);
        if (SPLITA) al[i] = *(const bf16x8*)((const char*)smem + 16384 + off);
      }
#pragma unroll
      for (int j = 0; j < 4; ++j) {
        const int row = wn * 64 + j * 16 + (lane & 15);
        const int off = row * 128 + ((gc ^ (row & 7)) << 4);
        bh[j] = *(const bf16x8*)((const char*)smem + BH_T * 16384 + off);
        bl[j] = *(const bf16x8*)((const char*)smem + (BH_T + 1) * 16384 + off);
      }
#pragma unroll
      for (int i = 0; i < 4; ++i)
#pragma unroll
        for (int j = 0; j < 4; ++j) {
          acc[i][j] = __builtin_amdgcn_mfma_f32_16x16x32_bf16(ah[i], bh[j], acc[i][j], 0, 0, 0);
          acc[i][j] = __builtin_amdgcn_mfma_f32_16x16x32_bf16(ah[i], bl[j], acc[i][j], 0, 0, 0);
          if (SPLITA)
            acc[i][j] = __builtin_amdgcn_mfma_f32_16x16x32_bf16(al[i], bh[j], acc[i][j], 0, 0, 0);
        }
    }
  }

  // epilogue: C/D layout col=lane&15, row=(lane>>4)*4+reg (m89-verified)
#pragma unroll
  for (int i = 0; i < 4; ++i) {
    const size_t rbase = m0 + wm * 64 + i * 16 + ((lane >> 4) << 2);
#pragma unroll
    for (int j = 0; j < 4; ++j) {
      const size_t col = n0 + wn * 64 + j * 16 + (lane & 15);
      const float bv = bias[col];
#pragma unroll
      for (int r = 0; r < 4; ++r)
        C[(rbase + r) * (size_t)N + col] = acc[i][j][r] + bv;
    }
  }
}

// ---------------- per-timestep GRU kernel ----------------
// 256 blocks x 256 thr (4 waves). Block owns 4 h-cols -> 12 w_hh rows (hi+lo) in
// swizzled LDS, staged via global_load_lds from pre-split planes. Each wave: one
// 16-batch M-tile, full K=1024, one 16-col B-tile (12 valid). 52 KiB static LDS.
__global__ __launch_bounds__(256, 2)
void gru_step(const float* __restrict__ xgc, const u16* __restrict__ whhhi,
              const u16* __restrict__ whhlo, const float* __restrict__ bhh,
              int t, int tc,
              const u16* __restrict__ Hhi, const u16* __restrict__ Hlo,
              u16* __restrict__ Nhi, u16* __restrict__ Nlo,
              u16* __restrict__ hs) {
  __shared__ __align__(16) u16 wbuf[2 * 12 * 1024];   // hi | lo, 48 KiB, T2-swizzled
  __shared__ float part[64 * 16];                     // 4 KiB

  const int tid = threadIdx.x, lane = tid & 63, wid = tid >> 6;
  const int jc0 = blockIdx.x << 2;                    // this block's first h-column

  // gate-thread identity + early loads (latency hidden under W-stage + MFMA)
  const int b = tid >> 2, j = tid & 3, col = jc0 + j;
  const size_t xbase = (size_t)(b * TCH + tc) * G3 + col;
  const float xr  = xgc[xbase];
  const float xz  = xgc[xbase + Hsz];
  const float xn_ = xgc[xbase + 2 * Hsz];
  const float bh_r = bhh[col], bh_z = bhh[Hsz + col], bh_n = bhh[2 * Hsz + col];
  const int hidx = b * Hsz + col;
  const float hprev = bf2f(Hhi[hidx]) + bf2f(Hlo[hidx]);

  // ---- stage W slice (12 rows hi + 12 lo): linear LDS dest + inverse-swizzled source ----
#pragma unroll
  for (int it = 0; it < 12; ++it) {
    const int g = (it % 6) * 256 + tid;               // granule in plane, 0..1535
    const int n = g >> 7, gslot = g & 127;
    const int gsrc = gslot ^ (n & 7);
    const int grow = (n >> 2) * Hsz + jc0 + (n & 3);  // rows 0-3:r, 4-7:z, 8-11:n
    const u16* src = (it < 6 ? whhhi : whhlo) + (size_t)grow * Hsz + gsrc * 8;
    u16* dst = wbuf + (it < 6 ? 0 : 12 * 1024) + (size_t)((it % 6) * 256 + wid * 64) * 8;
    __builtin_amdgcn_global_load_lds(
        (const __attribute__((address_space(1))) void*)src,
        (__attribute__((address_space(3))) void*)dst, 16, 0, 0);
  }
  __syncthreads();

  // ---- hg = h @ w_sliceᵀ (split x split, fp32 accum) ----
  const int mt = wid;                                 // M-tile: batches mt*16..+15
  const int brow = mt * 16 + (lane & 15);
  const int nr = lane & 15;
  const int nc = nr < 12 ? nr : 11;                   // clamp pad cols (unused results)

  f32x4 a_hh = (f32x4)0.f, a_hl = (f32x4)0.f, a_lh = (f32x4)0.f;
#pragma unroll 4
  for (int kt = 0; kt < 32; ++kt) {
    const int koff = (kt << 5) + ((lane >> 4) << 3);
    bf16x8 ahi = *(const bf16x8*)(Hhi + (size_t)brow * Hsz + koff);
    bf16x8 alo = *(const bf16x8*)(Hlo + (size_t)brow * Hsz + koff);
    const int gc = koff >> 3;
    const int boff = (nc << 11) + ((gc ^ (nc & 7)) << 4);
    bf16x8 bhi = *(const bf16x8*)((const char*)wbuf + boff);
    bf16x8 blo = *(const bf16x8*)((const char*)wbuf + 24576 + boff);
    a_hh = __builtin_amdgcn_mfma_f32_16x16x32_bf16(ahi, bhi, a_hh, 0, 0, 0);
    a_hl = __builtin_amdgcn_mfma_f32_16x16x32_bf16(ahi, blo, a_hl, 0, 0, 0);
    a_lh = __builtin_amdgcn_mfma_f32_16x16x32_bf16(alo, bhi, a_lh, 0, 0, 0);
  }
  const f32x4 asum = a_hh + a_hl + a_lh;

  // D layout: row=(lane>>4)*4+r (batch within tile), col=lane&15 (gate-row n)
  const int r0 = mt * 16 + ((lane >> 4) << 2);
#pragma unroll
  for (int r = 0; r < 4; ++r) part[(r0 + r) * 16 + nr] = asum[r];
  __syncthreads();

  // ---- fp32 gates (one (b,j) per thread) ----
  const float hr = part[b * 16 + j] + bh_r;
  const float hz = part[b * 16 + 4 + j] + bh_z;
  const float hn = part[b * 16 + 8 + j] + bh_n;
  const float rr = 1.f / (1.f + expf(-(xr + hr)));
  const float zz = 1.f / (1.f + expf(-(xz + hz)));
  const float nn = tanhf(xn_ + rr * hn);
  const float hnew = (1.f - zz) * nn + zz * hprev;
  u16 hi, lo; split2(hnew, hi, lo);
  Nhi[hidx] = hi; Nlo[hidx] = lo;                     // recurrence stays split (no drift)
  hs[(size_t)(b * Ssz + t) * Hsz + col] = hi;         // readout input: single bf16
}

// ---------------- launcher ----------------
extern "C" void kernel_launch(void* const* d_in, const int* in_sizes, int n_in,
                              void* d_out, int out_size, void* d_ws, size_t ws_size,
                              hipStream_t stream) {
  const float* x     = (const float*)d_in[0];
  const float* w_ih  = (const float*)d_in[1];
  const float* w_hh  = (const float*)d_in[2];
  const float* b_ih  = (const float*)d_in[3];
  const float* b_hh  = (const float*)d_in[4];
  const float* w_out = (const float*)d_in[5];
  const float* b_out = (const float*)d_in[6];
  float* out = (float*)d_out;

  if (ws_size < WS_TOTAL) {            // report the actual budget through the absmax signal
    diag_ws<<<1, 1, 0, stream>>>(out, (float)(ws_size >> 20));
    return;
  }

  char* ws = (char*)d_ws;
  u16* whhhi = (u16*)(ws + WHHHI_OFF);
  u16* whhlo = (u16*)(ws + WHHLO_OFF);
  u16* wihhi = (u16*)(ws + WIHHI_OFF);
  u16* wihlo = (u16*)(ws + WIHLO_OFF);
  u16* wohi  = (u16*)(ws + WOHI_OFF);
  u16* wolo  = (u16*)(ws + WOLO_OFF);
  u16* hsbuf = (u16*)(ws + HS_OFF);
  u16* hp    = (u16*)(ws + HP_OFF);
  u16* h0hi = hp;           u16* h0lo = hp + HPL;
  u16* h1hi = hp + 2 * HPL; u16* h1lo = hp + 3 * HPL;
  u16* xchi  = (u16*)(ws + XCHI_OFF);
  u16* xclo  = (u16*)(ws + XCLO_OFF);
  float* xgc = (float*)(ws + XGC_OFF);

  hipMemsetAsync(h0hi, 0, 2 * HPL * sizeof(u16), stream);   // h_0 = 0 (hi+lo planes)

  prep_w<<<2048, 256, 0, stream>>>(w_ih, w_hh, w_out,
                                   wihhi, wihlo, whhhi, whhlo, wohi, wolo);

  for (int c = 0; c < NCH; ++c) {
    prep_x<<<1024, 256, 0, stream>>>(x, c * TCH, xchi, xclo);
    // xg chunk = xc @ w_ihᵀ + b_ih : 32 x 24 tiles
    gemm_ws<true><<<768, 256, 0, stream>>>(xchi, xclo, wihhi, wihlo, b_ih, xgc, MCH, G3);
    for (int tcc = 0; tcc < TCH; ++tcc) {
      const int t = c * TCH + tcc;
      const u16* Hh = (t & 1) ? h1hi : h0hi;
      const u16* Hl = (t & 1) ? h1lo : h0lo;
      u16* Nh = (t & 1) ? h0hi : h1hi;
      u16* Nl = (t & 1) ? h0lo : h1lo;
      gru_step<<<256, 256, 0, stream>>>(xgc, whhhi, whhlo, b_hh, t, tcc,
                                        Hh, Hl, Nh, Nl, hsbuf);
    }
  }

  // out = hs @ w_outᵀ + b_out : 256 x 4 tiles
  gemm_ws<false><<<1024, 256, 0, stream>>>(hsbuf, nullptr, wohi, wolo, b_out, out, MR, OUTsz);
}